// Round 1
// baseline (102.667 us; speedup 1.0000x reference)
//
#include <hip/hip_runtime.h>
#include <hip/hip_bf16.h>
#include <math.h>

// Problem constants (fixed by reference setup_inputs)
constexpr int B = 2;
constexpr int N = 4096;   // pred points per batch
constexpr int M = 4096;   // target points per batch
constexpr int L = 512;    // latent dim

constexpr float KL_W = 0.001f;
constexpr float Q_W  = 0.1f;

// pairmin tiling
constexpr int THREADS = 256;
constexpr int QPT     = 2;               // queries per thread
constexpr int QC      = THREADS * QPT;   // 512 queries per block
constexpr int DT      = 512;             // data-tile points (8 KB LDS as float4)

constexpr int FLT_MAX_BITS = 0x7F7FFFFF;

// ws layout: int mins[3][B][N]  (dir 0 = pred->target, 1 = target->pred, 2 = pred->pred)
__global__ __launch_bounds__(256) void mgl_init_kernel(int* __restrict__ mins) {
    int idx = blockIdx.x * 256 + threadIdx.x;
    if (idx < 3 * B * N) mins[idx] = FLT_MAX_BITS;
}

__global__ __launch_bounds__(THREADS) void mgl_pairmin_kernel(
    const float* __restrict__ pred, const float* __restrict__ target,
    int* __restrict__ mins)
{
    __shared__ float4 tile[DT];

    const int z   = blockIdx.z;     // 0..5
    const int dir = z >> 1;         // z / B
    const int b   = z & 1;          // z % B

    const float* qbase;
    const float* dbase;
    int*         obase;
    if (dir == 0)      { qbase = pred   + b * N * 3; dbase = target + b * M * 3; obase = mins + (0 * B + b) * N; }
    else if (dir == 1) { qbase = target + b * M * 3; dbase = pred   + b * N * 3; obase = mins + (1 * B + b) * N; }
    else               { qbase = pred   + b * N * 3; dbase = pred   + b * N * 3; obase = mins + (2 * B + b) * N; }
    const bool self = (dir == 2);

    const int q0 = blockIdx.x * QC;
    const int d0 = blockIdx.y * DT;

    // stage data tile into LDS (float4-padded for ds_read_b128)
    for (int j = threadIdx.x; j < DT; j += THREADS) {
        const float* p = dbase + (size_t)(d0 + j) * 3;
        tile[j] = make_float4(p[0], p[1], p[2], 0.0f);
    }
    __syncthreads();

    const int qi0 = q0 + threadIdx.x;
    const int qi1 = qi0 + THREADS;

    const float qx0 = qbase[qi0 * 3 + 0];
    const float qy0 = qbase[qi0 * 3 + 1];
    const float qz0 = qbase[qi0 * 3 + 2];
    const float qx1 = qbase[qi1 * 3 + 0];
    const float qy1 = qbase[qi1 * 3 + 1];
    const float qz1 = qbase[qi1 * 3 + 2];

    float m0 = 3.402823466e+38f;
    float m1 = 3.402823466e+38f;

    if (!self) {
        #pragma unroll 4
        for (int j = 0; j < DT; ++j) {
            float4 t = tile[j];
            float dx = qx0 - t.x, dy = qy0 - t.y, dz = qz0 - t.z;
            float d  = fmaf(dz, dz, fmaf(dy, dy, dx * dx));
            m0 = fminf(m0, d);
            dx = qx1 - t.x; dy = qy1 - t.y; dz = qz1 - t.z;
            d  = fmaf(dz, dz, fmaf(dy, dy, dx * dx));
            m1 = fminf(m1, d);
        }
    } else {
        #pragma unroll 4
        for (int j = 0; j < DT; ++j) {
            float4 t = tile[j];
            const int dj = d0 + j;
            float dx = qx0 - t.x, dy = qy0 - t.y, dz = qz0 - t.z;
            float d  = fmaf(dz, dz, fmaf(dy, dy, dx * dx));
            d = (dj == qi0) ? 1.0e6f : d;   // reference masks diagonal with +1e6
            m0 = fminf(m0, d);
            dx = qx1 - t.x; dy = qy1 - t.y; dz = qz1 - t.z;
            d  = fmaf(dz, dz, fmaf(dy, dy, dx * dx));
            d = (dj == qi1) ? 1.0e6f : d;
            m1 = fminf(m1, d);
        }
    }

    // distances are >= 0 so float bit pattern is monotonic -> int atomicMin works
    atomicMin(obase + qi0, __float_as_int(m0));
    atomicMin(obase + qi1, __float_as_int(m1));
}

__global__ __launch_bounds__(256) void mgl_finalize_kernel(
    const int* __restrict__ mins, const float* __restrict__ mu,
    const float* __restrict__ logvar, float* __restrict__ out)
{
    const int tid = threadIdx.x;   // 256 threads

    double sPT[B], sTP[B], sPP[B], ssPP[B];
    #pragma unroll
    for (int b = 0; b < B; ++b) { sPT[b] = 0.0; sTP[b] = 0.0; sPP[b] = 0.0; ssPP[b] = 0.0; }
    double skl = 0.0;

    #pragma unroll
    for (int b = 0; b < B; ++b) {
        for (int i = tid; i < N; i += 256) {
            float vpt = __int_as_float(mins[(0 * B + b) * N + i]);
            float vtp = __int_as_float(mins[(1 * B + b) * N + i]);
            float vpp = __int_as_float(mins[(2 * B + b) * N + i]);
            sPT[b]  += (double)vpt;
            sTP[b]  += (double)vtp;
            sPP[b]  += (double)vpp;
            ssPP[b] += (double)vpp * (double)vpp;
        }
    }
    for (int i = tid; i < B * L; i += 256) {
        float m  = mu[i];
        float lv = logvar[i];
        skl += 1.0 + (double)lv - (double)m * (double)m - exp((double)lv);
    }

    __shared__ double red[256];
    auto bred = [&](double v) -> double {
        red[tid] = v;
        __syncthreads();
        for (int s = 128; s > 0; s >>= 1) {
            if (tid < s) red[tid] += red[tid + s];
            __syncthreads();
        }
        double r = red[0];
        __syncthreads();
        return r;
    };

    double tPT[B], tTP[B], tPP[B], tSS[B];
    #pragma unroll
    for (int b = 0; b < B; ++b) {
        tPT[b] = bred(sPT[b]);
        tTP[b] = bred(sTP[b]);
        tPP[b] = bred(sPP[b]);
        tSS[b] = bred(ssPP[b]);
    }
    double tKL = bred(skl);

    if (tid == 0) {
        double cd = 0.0;
        #pragma unroll
        for (int b = 0; b < B; ++b) cd += tPT[b] / (double)N + tTP[b] / (double)M;
        cd /= (double)B;

        double density = 0.0;
        #pragma unroll
        for (int b = 0; b < B; ++b) {
            double var = (tSS[b] - tPP[b] * tPP[b] / (double)N) / (double)(N - 1);
            density += sqrt(var > 0.0 ? var : 0.0);
        }
        density /= (double)B;

        double kl = -0.5 * tKL / (double)(B * L);

        double total = cd + (double)KL_W * kl + (double)Q_W * density;
        out[0] = (float)total;
        out[1] = (float)cd;
        out[2] = (float)kl;
        out[3] = (float)density;
    }
}

extern "C" void kernel_launch(void* const* d_in, const int* in_sizes, int n_in,
                              void* d_out, int out_size, void* d_ws, size_t ws_size,
                              hipStream_t stream) {
    const float* pred   = (const float*)d_in[0];
    const float* target = (const float*)d_in[1];
    const float* mu     = (const float*)d_in[2];
    const float* logvar = (const float*)d_in[3];
    float* out = (float*)d_out;

    int* mins = (int*)d_ws;   // 3*B*N ints = 96 KB

    mgl_init_kernel<<<dim3((3 * B * N + 255) / 256), 256, 0, stream>>>(mins);
    mgl_pairmin_kernel<<<dim3(N / QC, M / DT, 3 * B), THREADS, 0, stream>>>(pred, target, mins);
    mgl_finalize_kernel<<<1, 256, 0, stream>>>(mins, mu, logvar, out);
}